// Round 1
// baseline (1245.823 us; speedup 1.0000x reference)
//
#include <hip/hip_runtime.h>
#include <hip/hip_bf16.h>

// Sizes (fixed by the reference)
//  V=32000, T=48, E=128, HID=256, H=128, B=256, L=512, 4H=512
typedef unsigned short ushort_t;
typedef unsigned int uint_t;
typedef __bf16 bf16x8 __attribute__((ext_vector_type(8)));
typedef float f32x16 __attribute__((ext_vector_type(16)));

#define L2E 1.44269504088896340736f
#define LN2 0.69314718055994530942f

static __device__ __forceinline__ float fexp2(float x) { return __builtin_amdgcn_exp2f(x); }
static __device__ __forceinline__ float flog2(float x) { return __builtin_amdgcn_logf(x); }
static __device__ __forceinline__ float frcp (float x) { return __builtin_amdgcn_rcpf(x); }

static __device__ __forceinline__ float sigm(float x) {
  return frcp(1.0f + fexp2(-L2E * x));
}
static __device__ __forceinline__ float tanha(float x) {
  // tanh(x) = 1 - 2/(1+e^{2x})
  return 1.0f - 2.0f * frcp(1.0f + fexp2(2.0f * L2E * x));
}

static __device__ __forceinline__ ushort_t f2bf(float f) {
  union { float f; uint_t u; } v; v.f = f;
  uint_t u = v.u;
  uint_t r = (u + 0x7fffu + ((u >> 16) & 1u)) >> 16;  // RNE
  return (ushort_t)r;
}
static __device__ __forceinline__ float bf2f(ushort_t h) {
  union { uint_t u; float f; } v; v.u = ((uint_t)h) << 16;
  return v.f;
}
static __device__ __forceinline__ bf16x8 pack8(float4 a, float4 b) {
  uint4 u = make_uint4(
      (uint_t)f2bf(a.x) | ((uint_t)f2bf(a.y) << 16),
      (uint_t)f2bf(a.z) | ((uint_t)f2bf(a.w) << 16),
      (uint_t)f2bf(b.x) | ((uint_t)f2bf(b.y) << 16),
      (uint_t)f2bf(b.z) | ((uint_t)f2bf(b.w) << 16));
  return __builtin_bit_cast(bf16x8, u);
}
static __device__ __forceinline__ bf16x8 zero8() {
  uint4 z = make_uint4(0u, 0u, 0u, 0u);
  return __builtin_bit_cast(bf16x8, z);
}

// ---------------------------------------------------------------------------
// K0: embedding gather -> x_bt[b][t][128] (bf16)
// ---------------------------------------------------------------------------
__global__ void k0_embed(const int* __restrict__ words,
                         const float* __restrict__ emb,
                         ushort_t* __restrict__ x_bt) {
  int i = blockIdx.x * 256 + threadIdx.x;      // < 256*512*128 = 16777216
  int row = i >> 7;                             // b*512 + t
  int e = i & 127;
  x_bt[i] = f2bf(emb[words[row] * 128 + e]);
}

// ---------------------------------------------------------------------------
// K2: fused BiLSTM recurrence.
// grid = 256 WGs x 512 thr. wg>>7 = dir, (wg&127)*2 = batch rows (2 per WG).
// Weights [Whh|Wih] (K=256, N=512) register-resident as 32x32x16 B-fragments.
// A-tile rows 0,1 = [h | x_t] (bf16, LDS, permuted slot layout), rows 2..31 = 0.
// ---------------------------------------------------------------------------
__global__ __launch_bounds__(512, 2) void k2_lstm(
    const float* __restrict__ Wih_f, const float* __restrict__ Whh_f,
    const float* __restrict__ bih_f, const float* __restrict__ bhh_f,
    const float* __restrict__ Wih_b, const float* __restrict__ Whh_b,
    const float* __restrict__ bih_b, const float* __restrict__ bhh_b,
    const ushort_t* __restrict__ x_bt,
    ushort_t* __restrict__ h_f, ushort_t* __restrict__ h_b) {
  const int wg = blockIdx.x;
  const int dir = wg >> 7;
  const int r0 = (wg & 127) << 1;
  const float* Whh = dir ? Whh_b : Whh_f;
  const float* Wih = dir ? Wih_b : Wih_f;
  const float* bih = dir ? bih_b : bih_f;
  const float* bhh = dir ? bhh_b : bhh_f;
  ushort_t* hout = dir ? h_b : h_f;

  const int tid = threadIdx.x;
  const int w = tid >> 6;        // wave 0..7, owns gate tiles 2w, 2w+1
  const int lane = tid & 63;
  const int m31 = lane & 31;
  const int q = lane >> 5;

  // hx[r][slot]: row r (batch row r0+r), 256 slots = permuted [h(128)|x(128)]
  // slot(k) = ((k>>3)&1)*128 + (k>>4)*8 + (k&7); frag chunk c at q*128+c*8
  __shared__ __align__(16) ushort_t hx[2][256];
  __shared__ __align__(16) float gl[512][2];   // gates [g][row]

  // ---- load register-resident weight fragments (bf16) ----
  bf16x8 wf[2][16];
#pragma unroll
  for (int T = 0; T < 2; ++T) {
    const int n = ((w << 1) + T) * 32 + m31;   // gate index for this lane
#pragma unroll
    for (int c = 0; c < 16; ++c) {
      const float* src = (c < 8) ? (Whh + n * 128 + c * 16 + q * 8)
                                 : (Wih + n * 128 + (c - 8) * 16 + q * 8);
      float4 lo = *(const float4*)(src);
      float4 hi = *(const float4*)(src + 4);
      wf[T][c] = pack8(lo, hi);
    }
  }

  // ---- per-update-thread state (threads 0..255: r=tid>>7, j=tid&127) ----
  const int ur = (tid >> 7) & 1;
  const int uj = tid & 127;
  const int slot = (((uj >> 3) & 1) << 7) + ((uj >> 4) << 3) + (uj & 7);
  float b_i = 0.f, b_f = 0.f, b_g = 0.f, b_o = 0.f;
  float cst = 0.f;
  if (tid < 256) {
    b_i = bih[uj] + bhh[uj];
    b_f = bih[128 + uj] + bhh[128 + uj];
    b_g = bih[256 + uj] + bhh[256 + uj];
    b_o = bih[384 + uj] + bhh[384 + uj];
    const int te0 = dir ? 511 : 0;
    hx[ur][slot] = 0;  // h(-1) = 0
    hx[ur][slot + 64] = x_bt[((r0 + ur) * 512 + te0) * 128 + uj];
  }
  __syncthreads();

  const ushort_t* hp = &hx[0][0] + (m31 < 2 ? m31 : 1) * 256;
  const bool act = (m31 < 2);

#pragma unroll 1
  for (int t = 0; t < 512; ++t) {
    const int te = dir ? (511 - t) : t;
    // prefetch next step's x (consumed after barrier1)
    ushort_t xnext = 0;
    if (tid < 256) {
      int tn = dir ? (510 - t) : (t + 1);
      tn = min(511, max(0, tn));
      xnext = x_bt[((r0 + ur) * 512 + tn) * 128 + uj];
    }
    // ---- MFMA phase: gates = [h|x] @ [Whh|Wih]^T ----
    f32x16 a0{}, a1{}, p0{}, p1{};
#pragma unroll
    for (int c = 0; c < 16; ++c) {
      uint4 araw = make_uint4(0u, 0u, 0u, 0u);
      if (act) araw = *(const uint4*)(hp + (q << 7) + (c << 3));
      bf16x8 af = __builtin_bit_cast(bf16x8, araw);
      if (c & 1) {
        p0 = __builtin_amdgcn_mfma_f32_32x32x16_bf16(af, wf[0][c], p0, 0, 0, 0);
        p1 = __builtin_amdgcn_mfma_f32_32x32x16_bf16(af, wf[1][c], p1, 0, 0, 0);
      } else {
        a0 = __builtin_amdgcn_mfma_f32_32x32x16_bf16(af, wf[0][c], a0, 0, 0, 0);
        a1 = __builtin_amdgcn_mfma_f32_32x32x16_bf16(af, wf[1][c], a1, 0, 0, 0);
      }
    }
    // C/D: col=lane&31, row=(reg&3)+8*(reg>>2)+4*(lane>>5). rows 0,1 on lanes<32, regs 0,1.
    if (lane < 32) {
      const int g0 = (w << 6) + m31;
      *(float2*)&gl[g0][0]      = make_float2(a0[0] + p0[0], a0[1] + p0[1]);
      *(float2*)&gl[g0 + 32][0] = make_float2(a1[0] + p1[0], a1[1] + p1[1]);
    }
    __syncthreads();   // barrier1: gates visible; prior A-reads done
    if (tid < 256) {
      float gi = gl[uj][ur] + b_i;
      float gf = gl[128 + uj][ur] + b_f;
      float gg = gl[256 + uj][ur] + b_g;
      float go = gl[384 + uj][ur] + b_o;
      float si = sigm(gi), sf = sigm(gf), so = sigm(go);
      float tg = tanha(gg);
      cst = sf * cst + si * tg;
      float h = so * tanha(cst);
      ushort_t hb = f2bf(h);
      hx[ur][slot] = hb;
      hx[ur][slot + 64] = xnext;
      hout[(te * 256 + r0 + ur) * 128 + uj] = hb;
    }
    __syncthreads();   // barrier2: h/x visible for next step
  }
}

// ---------------------------------------------------------------------------
// K3: emis[t*256+b][48] = [h_f|h_b] @ Wout^T + bout  (fp32 out)
// grid = 1024 WGs x 256 thr; wave handles 32 rows, 2 N-tiles (48 cols + pad)
// ---------------------------------------------------------------------------
__global__ __launch_bounds__(256, 2) void k3_emis(
    const ushort_t* __restrict__ h_f, const ushort_t* __restrict__ h_b,
    const float* __restrict__ Wout, const float* __restrict__ bout,
    float* __restrict__ emis) {
  const int w = threadIdx.x >> 6;
  const int lane = threadIdx.x & 63;
  const int m31 = lane & 31;
  const int q = lane >> 5;
  const int Mbase = blockIdx.x * 128 + w * 32;

  bf16x8 bfr[2][16];
  float bo[2];
#pragma unroll
  for (int T = 0; T < 2; ++T) {
    const int n = T * 32 + m31;
    if (n < 48) {
      bo[T] = bout[n];
#pragma unroll
      for (int c = 0; c < 16; ++c) {
        const float* src = Wout + n * 256 + c * 16 + q * 8;
        bfr[T][c] = pack8(*(const float4*)src, *(const float4*)(src + 4));
      }
    } else {
      bo[T] = 0.f;
#pragma unroll
      for (int c = 0; c < 16; ++c) bfr[T][c] = zero8();
    }
  }
  f32x16 acc0{}, acc1{};
  const ushort_t* hrf = h_f + (long)(Mbase + m31) * 128;
  const ushort_t* hrb = h_b + (long)(Mbase + m31) * 128;
#pragma unroll
  for (int c = 0; c < 16; ++c) {
    const ushort_t* src = (c < 8) ? (hrf + c * 16 + q * 8) : (hrb + (c - 8) * 16 + q * 8);
    bf16x8 af = __builtin_bit_cast(bf16x8, *(const uint4*)src);
    acc0 = __builtin_amdgcn_mfma_f32_32x32x16_bf16(af, bfr[0][c], acc0, 0, 0, 0);
    acc1 = __builtin_amdgcn_mfma_f32_32x32x16_bf16(af, bfr[1][c], acc1, 0, 0, 0);
  }
#pragma unroll
  for (int T = 0; T < 2; ++T) {
    const int n = T * 32 + m31;
    if (n >= 48) continue;
    f32x16 A = T ? acc1 : acc0;
#pragma unroll
    for (int r = 0; r < 16; ++r) {
      const int row = (r & 3) + ((r >> 2) << 3) + (q << 2);
      emis[(long)(Mbase + row) * 48 + n] = A[r] + bo[T];
    }
  }
}

// ---------------------------------------------------------------------------
// K4: CRF forward (denominator). 256 WGs x 64 thr, one batch row per wave.
// den'[j] = M + log2(sum_i 2^{den_i - M} * P[i][j]) + emis_j*log2e,
// P[i][j] = 2^{trans[i][j]*log2e} precomputed in registers (lane j = col j).
// Lag-1 max with 2-iteration pipeline slack.
// ---------------------------------------------------------------------------
__global__ void k4_den(const int* __restrict__ words, const float* __restrict__ emis,
                       const float* __restrict__ trans, const float* __restrict__ st,
                       const float* __restrict__ et, float* __restrict__ denom) {
  const int b = blockIdx.x;
  const int j = threadIdx.x;
  const bool v = j < 48;
  const int jj = v ? j : 47;
  float pcol[48];
#pragma unroll
  for (int i = 0; i < 48; ++i) pcol[i] = fexp2(trans[i * 48 + jj] * L2E);

  __shared__ __align__(16) float ul[64];
  float den2 = v ? (st[j] + emis[b * 48 + j]) * L2E : -3e38f;
  const float e2 = v ? et[j] * L2E : 0.f;

  float M0 = den2;
#pragma unroll
  for (int d = 32; d; d >>= 1) M0 = fmaxf(M0, __shfl_xor(M0, d, 64));
  float Muse = M0, Mcur = M0;

#pragma unroll 1
  for (int t = 1; t < 512; ++t) {
    const float em = v ? emis[(t * 256 + b) * 48 + j] : 0.f;
    const int wv = words[b * 512 + t];
    float u = fexp2(den2 - Muse);
    ul[j] = v ? u : 0.f;
    __syncthreads();
    float s0 = 0.f, s1 = 0.f, s2 = 0.f, s3 = 0.f;
#pragma unroll
    for (int i4 = 0; i4 < 12; ++i4) {
      float4 uu = *(const float4*)&ul[i4 * 4];
      s0 = fmaf(uu.x, pcol[i4 * 4 + 0], s0);
      s1 = fmaf(uu.y, pcol[i4 * 4 + 1], s1);
      s2 = fmaf(uu.z, pcol[i4 * 4 + 2], s2);
      s3 = fmaf(uu.w, pcol[i4 * 4 + 3], s3);
    }
    float nd = Muse + flog2((s0 + s1) + (s2 + s3)) + em * L2E;
    float newden = (wv != 0) ? nd : den2;
    newden = v ? newden : -3e38f;
    float Mn = newden;
#pragma unroll
    for (int d = 32; d; d >>= 1) Mn = fmaxf(Mn, __shfl_xor(Mn, d, 64));
    den2 = newden;
    Muse = Mcur;   // use max from 2 iterations back next step (latency slack)
    Mcur = Mn;
  }
  float dd = v ? (den2 + e2) : -3e38f;
  float Mf = dd;
#pragma unroll
  for (int d = 32; d; d >>= 1) Mf = fmaxf(Mf, __shfl_xor(Mf, d, 64));
  float uf = fexp2(dd - Mf);
#pragma unroll
  for (int d = 32; d; d >>= 1) uf += __shfl_xor(uf, d, 64);
  if (j == 0) denom[b] = (Mf + flog2(uf)) * LN2;
}

// ---------------------------------------------------------------------------
// K4b: CRF numerator (gold path score). 256 WGs x 64 thr, parallel over t.
// ---------------------------------------------------------------------------
__global__ void k4b_num(const int* __restrict__ words, const int* __restrict__ tags,
                        const float* __restrict__ emis, const float* __restrict__ trans,
                        const float* __restrict__ st, const float* __restrict__ et,
                        float* __restrict__ num) {
  const int b = blockIdx.x;
  const int lane = threadIdx.x;
  float s = 0.f;
  int cnt = 0;
#pragma unroll 1
  for (int s8 = 0; s8 < 8; ++s8) {
    const int t = lane + (s8 << 6);
    const int wv = words[b * 512 + t];
    const int tg = tags[b * 512 + t];
    const bool mt = (wv != 0);
    cnt += mt ? 1 : 0;
    if (t == 0) {
      s += st[tg] + emis[b * 48 + tg];
    } else if (mt) {
      const int tp = tags[b * 512 + t - 1];
      s += trans[tp * 48 + tg] + emis[(t * 256 + b) * 48 + tg];
    }
  }
#pragma unroll
  for (int d = 32; d; d >>= 1) {
    s += __shfl_xor(s, d, 64);
    cnt += __shfl_xor(cnt, d, 64);
  }
  if (lane == 0) {
    const int lt = tags[b * 512 + cnt - 1];
    num[b] = s + et[lt];
  }
}

// ---------------------------------------------------------------------------
// K5: loss = -mean(num - denom)
// ---------------------------------------------------------------------------
__global__ void k5_loss(const float* __restrict__ num, const float* __restrict__ denom,
                        float* __restrict__ out) {
  const int tid = threadIdx.x;
  float v = num[tid] - denom[tid];
#pragma unroll
  for (int d = 32; d; d >>= 1) v += __shfl_xor(v, d, 64);
  __shared__ float p[4];
  if ((tid & 63) == 0) p[tid >> 6] = v;
  __syncthreads();
  if (tid == 0) out[0] = -(p[0] + p[1] + p[2] + p[3]) * (1.0f / 256.0f);
}

// ---------------------------------------------------------------------------
extern "C" void kernel_launch(void* const* d_in, const int* in_sizes, int n_in,
                              void* d_out, int out_size, void* d_ws, size_t ws_size,
                              hipStream_t stream) {
  (void)in_sizes; (void)n_in; (void)out_size; (void)ws_size;
  const int*   words = (const int*)d_in[0];
  const int*   tags  = (const int*)d_in[1];
  // d_in[2] = mask (bool) -- unused; reconstructed as words != 0
  const float* emb   = (const float*)d_in[3];
  const float* Wih_f = (const float*)d_in[4];
  const float* Whh_f = (const float*)d_in[5];
  const float* bih_f = (const float*)d_in[6];
  const float* bhh_f = (const float*)d_in[7];
  const float* Wih_b = (const float*)d_in[8];
  const float* Whh_b = (const float*)d_in[9];
  const float* bih_b = (const float*)d_in[10];
  const float* bhh_b = (const float*)d_in[11];
  const float* Wout  = (const float*)d_in[12];
  const float* bout  = (const float*)d_in[13];
  const float* trans = (const float*)d_in[14];
  const float* st    = (const float*)d_in[15];
  const float* et    = (const float*)d_in[16];

  char* ws = (char*)d_ws;
  ushort_t* x_bt  = (ushort_t*)(ws);                    // 33,554,432 B
  ushort_t* h_f   = (ushort_t*)(ws + 33554432);         // 33,554,432 B
  ushort_t* h_b   = (ushort_t*)(ws + 67108864);         // 33,554,432 B
  float*    emis  = (float*)   (ws + 100663296);        // 25,165,824 B
  float*    denom = (float*)   (ws + 125829120);        // 1,024 B
  float*    num   = (float*)   (ws + 125830144);        // 1,024 B
  // total ws needed: 125,831,168 B (~120 MiB)

  k0_embed<<<65536, 256, 0, stream>>>(words, emb, x_bt);
  k2_lstm <<<256, 512, 0, stream>>>(Wih_f, Whh_f, bih_f, bhh_f,
                                    Wih_b, Whh_b, bih_b, bhh_b,
                                    x_bt, h_f, h_b);
  k3_emis <<<1024, 256, 0, stream>>>(h_f, h_b, Wout, bout, emis);
  k4_den  <<<256, 64, 0, stream>>>(words, emis, trans, st, et, denom);
  k4b_num <<<256, 64, 0, stream>>>(words, tags, emis, trans, st, et, num);
  k5_loss <<<1, 256, 0, stream>>>(num, denom, (float*)d_out);
}

// Round 2
// 906.324 us; speedup vs baseline: 1.3746x; 1.3746x over previous
//
#include <hip/hip_runtime.h>
#include <hip/hip_bf16.h>

// Sizes (fixed by the reference)
//  V=32000, T=48, E=128, HID=256, H=128, B=256, L=512, 4H=512
typedef unsigned short ushort_t;
typedef unsigned int uint_t;
typedef __bf16 bf16x8 __attribute__((ext_vector_type(8)));
typedef float f32x4 __attribute__((ext_vector_type(4)));
typedef float f32x16 __attribute__((ext_vector_type(16)));

#define L2E 1.44269504088896340736f
#define LN2 0.69314718055994530942f

// LDS-only barrier: does NOT drain vmcnt, so global loads/stores issued in a
// step stay in flight across the barrier (the __syncthreads vmcnt(0) drain was
// the round-1 critical-path killer in k2/k4).
#define WGBAR() __asm__ volatile("s_waitcnt lgkmcnt(0)\n\ts_barrier" ::: "memory")
// In-wave LDS RAW fence for single-wave workgroups.
#define LGKM0() __asm__ volatile("s_waitcnt lgkmcnt(0)" ::: "memory")

static __device__ __forceinline__ float fexp2(float x) { return __builtin_amdgcn_exp2f(x); }
static __device__ __forceinline__ float flog2(float x) { return __builtin_amdgcn_logf(x); }
static __device__ __forceinline__ float frcp (float x) { return __builtin_amdgcn_rcpf(x); }

static __device__ __forceinline__ float sigm(float x) {
  return frcp(1.0f + fexp2(-L2E * x));
}
static __device__ __forceinline__ float tanha(float x) {
  return 1.0f - 2.0f * frcp(1.0f + fexp2(2.0f * L2E * x));
}

static __device__ __forceinline__ ushort_t f2bf(float f) {
  union { float f; uint_t u; } v; v.f = f;
  uint_t u = v.u;
  uint_t r = (u + 0x7fffu + ((u >> 16) & 1u)) >> 16;  // RNE
  return (ushort_t)r;
}
static __device__ __forceinline__ bf16x8 pack8(float4 a, float4 b) {
  uint4 u = make_uint4(
      (uint_t)f2bf(a.x) | ((uint_t)f2bf(a.y) << 16),
      (uint_t)f2bf(a.z) | ((uint_t)f2bf(a.w) << 16),
      (uint_t)f2bf(b.x) | ((uint_t)f2bf(b.y) << 16),
      (uint_t)f2bf(b.z) | ((uint_t)f2bf(b.w) << 16));
  return __builtin_bit_cast(bf16x8, u);
}
static __device__ __forceinline__ bf16x8 zero8() {
  uint4 z = make_uint4(0u, 0u, 0u, 0u);
  return __builtin_bit_cast(bf16x8, z);
}

// ---------------------------------------------------------------------------
// K0: embedding gather -> x_bt[b][t][128] (bf16)
// ---------------------------------------------------------------------------
__global__ void k0_embed(const int* __restrict__ words,
                         const float* __restrict__ emb,
                         ushort_t* __restrict__ x_bt) {
  int i = blockIdx.x * 256 + threadIdx.x;      // < 16777216
  int row = i >> 7;                             // b*512 + t
  int e = i & 127;
  x_bt[i] = f2bf(emb[words[row] * 128 + e]);
}

// ---------------------------------------------------------------------------
// K2 v2: fused BiLSTM recurrence, 16x16x32 tiles, 1 raw barrier per step.
// grid = 256 WGs x 512 thr. wg>>7 = dir, (wg&127)*2 = batch rows (2 per WG).
// Wave w owns gate cols j = w*16..w*16+15 for all 4 quadrants (i,f,g,o):
// gates land in the wave's own C-regs -> in-wave shuffle, no LDS round-trip.
// hx double buffer: [buf][row][k] with k = [h(0..127) | x(128..255)], linear.
// Global x prefetch depth-2 (regs) + per-step global h store stay in flight
// across the raw barrier (no vmcnt drain).
// ---------------------------------------------------------------------------
__global__ __launch_bounds__(512, 2) void k2_lstm(
    const float* __restrict__ Wih_f, const float* __restrict__ Whh_f,
    const float* __restrict__ bih_f, const float* __restrict__ bhh_f,
    const float* __restrict__ Wih_b, const float* __restrict__ Whh_b,
    const float* __restrict__ bih_b, const float* __restrict__ bhh_b,
    const ushort_t* __restrict__ x_bt,
    ushort_t* __restrict__ h_f, ushort_t* __restrict__ h_b) {
  const int wg = blockIdx.x;
  const int dir = wg >> 7;
  const int r0 = (wg & 127) << 1;
  const float* Whh = dir ? Whh_b : Whh_f;
  const float* Wih = dir ? Wih_b : Wih_f;
  const float* bih = dir ? bih_b : bih_f;
  const float* bhh = dir ? bhh_b : bhh_f;
  ushort_t* hout = dir ? h_b : h_f;

  const int tid = threadIdx.x;
  const int w = tid >> 6;        // wave 0..7
  const int lane = tid & 63;
  const int l15 = lane & 15;
  const int kq = lane >> 4;      // 0..3

  __shared__ __align__(16) ushort_t hx[2][2][256];  // 2 KiB

  // ---- register-resident B-fragments: 4 quadrants x 8 K-chunks ----
  // B lane layout (16x16x32): col n = lane&15, k = (lane>>4)*8 + j
  bf16x8 wf[4][8];
#pragma unroll
  for (int Q = 0; Q < 4; ++Q) {
    const int n = Q * 128 + w * 16 + l15;
#pragma unroll
    for (int c = 0; c < 8; ++c) {
      const int k0 = c * 32 + kq * 8;
      const float* src = (c < 4) ? (Whh + n * 128 + k0)
                                 : (Wih + n * 128 + (k0 - 128));
      wf[Q][c] = pack8(*(const float4*)src, *(const float4*)(src + 4));
    }
  }

  // update lanes: lane<32 handles (row ur, col uj)
  const int ur = (lane >> 4) & 1;
  const int uj = w * 16 + l15;
  float bQ[4];
#pragma unroll
  for (int Q = 0; Q < 4; ++Q) bQ[Q] = bih[Q * 128 + uj] + bhh[Q * 128 + uj];
  float cst = 0.f;

  // ---- init: hx[0] = [h=0 | x(t=0)]; preload xr = x(t=1) ----
  if (tid < 256) {
    const int r = tid >> 7, j = tid & 127;
    const int t0 = dir ? 511 : 0;
    hx[0][r][j] = 0;
    hx[0][r][128 + j] = x_bt[((r0 + r) * 512 + t0) * 128 + j];
  }
  uint4 xr = make_uint4(0, 0, 0, 0), xr2 = make_uint4(0, 0, 0, 0);
  if (w == 0 && lane < 32) {
    const int r = lane >> 4;
    const int t1 = dir ? 510 : 1;
    xr = *(const uint4*)(x_bt + ((r0 + r) * 512 + t1) * 128 + l15 * 8);
  }
  WGBAR();

#pragma unroll 1
  for (int t = 0; t < 512; ++t) {
    const int p = t & 1;
    // wave0: prefetch x(t+2) -> xr2; write x(t+1) (=xr) into hx[p^1]
    if (w == 0 && lane < 32) {
      const int r = lane >> 4;
      const int s2 = min(511, t + 2);
      const int ts2 = dir ? (511 - s2) : s2;
      xr2 = *(const uint4*)(x_bt + ((r0 + r) * 512 + ts2) * 128 + l15 * 8);
      *(uint4*)(&hx[p ^ 1][r][128 + l15 * 8]) = xr;
    }
    // ---- A reads + MFMA. A lane layout: row lane&15 (clamped to 0/1), k=(lane>>4)*8+j
    f32x4 a0{}, a1{}, a2{}, a3{};
    const ushort_t* abase = &hx[p][l15 & 1][kq * 8];
#pragma unroll
    for (int c = 0; c < 8; ++c) {
      bf16x8 af = __builtin_bit_cast(bf16x8, *(const uint4*)(abase + c * 32));
      a0 = __builtin_amdgcn_mfma_f32_16x16x32_bf16(af, wf[0][c], a0, 0, 0, 0);
      a1 = __builtin_amdgcn_mfma_f32_16x16x32_bf16(af, wf[1][c], a1, 0, 0, 0);
      a2 = __builtin_amdgcn_mfma_f32_16x16x32_bf16(af, wf[2][c], a2, 0, 0, 0);
      a3 = __builtin_amdgcn_mfma_f32_16x16x32_bf16(af, wf[3][c], a3, 0, 0, 0);
    }
    // ---- redistribute: C/D row 0 = reg0 lanes 0-15, row 1 = reg1 lanes 0-15.
    // Target: lane l'<32 gets (row l'>>4, col l'&15) for all 4 quadrants.
    float g0, g1, g2, g3;
    {
      float t0, t1;
      t0 = __shfl(a0[0], l15, 64); t1 = __shfl(a0[1], l15, 64); g0 = (lane < 16) ? t0 : t1;
      t0 = __shfl(a1[0], l15, 64); t1 = __shfl(a1[1], l15, 64); g1 = (lane < 16) ? t0 : t1;
      t0 = __shfl(a2[0], l15, 64); t1 = __shfl(a2[1], l15, 64); g2 = (lane < 16) ? t0 : t1;
      t0 = __shfl(a3[0], l15, 64); t1 = __shfl(a3[1], l15, 64); g3 = (lane < 16) ? t0 : t1;
    }
    if (lane < 32) {
      const float gi = g0 + bQ[0];
      const float gf = g1 + bQ[1];
      const float gg = g2 + bQ[2];
      const float go = g3 + bQ[3];
      const float si = sigm(gi), sf = sigm(gf), so = sigm(go);
      const float tg = tanha(gg);
      cst = sf * cst + si * tg;
      const float h = so * tanha(cst);
      const ushort_t hb = f2bf(h);
      hx[p ^ 1][ur][uj] = hb;                       // next step's A (h part)
      const int te = dir ? (511 - t) : t;
      hout[(te * 256 + r0 + ur) * 128 + uj] = hb;   // global store, stays in flight
    }
    WGBAR();
    if (w == 0) xr = xr2;
  }
}

// ---------------------------------------------------------------------------
// K3: emis[t*256+b][48] = [h_f|h_b] @ Wout^T + bout  (fp32 out)  [unchanged]
// ---------------------------------------------------------------------------
__global__ __launch_bounds__(256, 2) void k3_emis(
    const ushort_t* __restrict__ h_f, const ushort_t* __restrict__ h_b,
    const float* __restrict__ Wout, const float* __restrict__ bout,
    float* __restrict__ emis) {
  const int w = threadIdx.x >> 6;
  const int lane = threadIdx.x & 63;
  const int m31 = lane & 31;
  const int q = lane >> 5;
  const int Mbase = blockIdx.x * 128 + w * 32;

  bf16x8 bfr[2][16];
  float bo[2];
#pragma unroll
  for (int T = 0; T < 2; ++T) {
    const int n = T * 32 + m31;
    if (n < 48) {
      bo[T] = bout[n];
#pragma unroll
      for (int c = 0; c < 16; ++c) {
        const float* src = Wout + n * 256 + c * 16 + q * 8;
        bfr[T][c] = pack8(*(const float4*)src, *(const float4*)(src + 4));
      }
    } else {
      bo[T] = 0.f;
#pragma unroll
      for (int c = 0; c < 16; ++c) bfr[T][c] = zero8();
    }
  }
  f32x16 acc0{}, acc1{};
  const ushort_t* hrf = h_f + (long)(Mbase + m31) * 128;
  const ushort_t* hrb = h_b + (long)(Mbase + m31) * 128;
#pragma unroll
  for (int c = 0; c < 16; ++c) {
    const ushort_t* src = (c < 8) ? (hrf + c * 16 + q * 8) : (hrb + (c - 8) * 16 + q * 8);
    bf16x8 af = __builtin_bit_cast(bf16x8, *(const uint4*)src);
    acc0 = __builtin_amdgcn_mfma_f32_32x32x16_bf16(af, bfr[0][c], acc0, 0, 0, 0);
    acc1 = __builtin_amdgcn_mfma_f32_32x32x16_bf16(af, bfr[1][c], acc1, 0, 0, 0);
  }
#pragma unroll
  for (int T = 0; T < 2; ++T) {
    const int n = T * 32 + m31;
    if (n >= 48) continue;
    f32x16 A = T ? acc1 : acc0;
#pragma unroll
    for (int r = 0; r < 16; ++r) {
      const int row = (r & 3) + ((r >> 2) << 3) + (q << 2);
      emis[(long)(Mbase + row) * 48 + n] = A[r] + bo[T];
    }
  }
}

// ---------------------------------------------------------------------------
// K4 v2: CRF forward (denominator). 256 WGs x 64 thr (single wave).
// emis/words prefetched depth-3 (no barrier -> loads never drained).
// ---------------------------------------------------------------------------
__global__ void k4_den(const int* __restrict__ words, const float* __restrict__ emis,
                       const float* __restrict__ trans, const float* __restrict__ st,
                       const float* __restrict__ et, float* __restrict__ denom) {
  const int b = blockIdx.x;
  const int j = threadIdx.x;
  const bool v = j < 48;
  const int jj = v ? j : 47;
  float pcol[48];
#pragma unroll
  for (int i = 0; i < 48; ++i) pcol[i] = fexp2(trans[i * 48 + jj] * L2E);

  __shared__ __align__(16) float ul[64];
  float den2 = v ? (st[j] + emis[b * 48 + j]) * L2E : -3e38f;
  const float e2 = v ? et[j] * L2E : 0.f;

  float M0 = den2;
#pragma unroll
  for (int d = 32; d; d >>= 1) M0 = fmaxf(M0, __shfl_xor(M0, d, 64));
  float Muse = M0, Mcur = M0;

  // prefetch pipeline depth 3
  float em0 = v ? emis[(1 * 256 + b) * 48 + j] : 0.f;
  float em1 = v ? emis[(2 * 256 + b) * 48 + j] : 0.f;
  float em2 = v ? emis[(3 * 256 + b) * 48 + j] : 0.f;
  int wv0 = words[b * 512 + 1];
  int wv1 = words[b * 512 + 2];
  int wv2 = words[b * 512 + 3];

#pragma unroll 1
  for (int t = 1; t < 512; ++t) {
    const float em = em0;
    const int wv = wv0;
    const int tn = min(511, t + 3);
    em0 = em1; em1 = em2;
    em2 = v ? emis[(tn * 256 + b) * 48 + j] : 0.f;
    wv0 = wv1; wv1 = wv2;
    wv2 = words[b * 512 + tn];

    float u = fexp2(den2 - Muse);
    ul[j] = v ? u : 0.f;
    LGKM0();
    float s0 = 0.f, s1 = 0.f, s2 = 0.f, s3 = 0.f;
#pragma unroll
    for (int i4 = 0; i4 < 12; ++i4) {
      float4 uu = *(const float4*)&ul[i4 * 4];
      s0 = fmaf(uu.x, pcol[i4 * 4 + 0], s0);
      s1 = fmaf(uu.y, pcol[i4 * 4 + 1], s1);
      s2 = fmaf(uu.z, pcol[i4 * 4 + 2], s2);
      s3 = fmaf(uu.w, pcol[i4 * 4 + 3], s3);
    }
    float nd = Muse + flog2((s0 + s1) + (s2 + s3)) + em * L2E;
    float newden = (wv != 0) ? nd : den2;
    newden = v ? newden : -3e38f;
    float Mn = newden;
#pragma unroll
    for (int d = 32; d; d >>= 1) Mn = fmaxf(Mn, __shfl_xor(Mn, d, 64));
    den2 = newden;
    Muse = Mcur;   // lag-2 max: off the critical path
    Mcur = Mn;
  }
  float dd = v ? (den2 + e2) : -3e38f;
  float Mf = dd;
#pragma unroll
  for (int d = 32; d; d >>= 1) Mf = fmaxf(Mf, __shfl_xor(Mf, d, 64));
  float uf = fexp2(dd - Mf);
#pragma unroll
  for (int d = 32; d; d >>= 1) uf += __shfl_xor(uf, d, 64);
  if (j == 0) denom[b] = (Mf + flog2(uf)) * LN2;
}

// ---------------------------------------------------------------------------
// K4b: CRF numerator (gold path score). [unchanged]
// ---------------------------------------------------------------------------
__global__ void k4b_num(const int* __restrict__ words, const int* __restrict__ tags,
                        const float* __restrict__ emis, const float* __restrict__ trans,
                        const float* __restrict__ st, const float* __restrict__ et,
                        float* __restrict__ num) {
  const int b = blockIdx.x;
  const int lane = threadIdx.x;
  float s = 0.f;
  int cnt = 0;
#pragma unroll 1
  for (int s8 = 0; s8 < 8; ++s8) {
    const int t = lane + (s8 << 6);
    const int wv = words[b * 512 + t];
    const int tg = tags[b * 512 + t];
    const bool mt = (wv != 0);
    cnt += mt ? 1 : 0;
    if (t == 0) {
      s += st[tg] + emis[b * 48 + tg];
    } else if (mt) {
      const int tp = tags[b * 512 + t - 1];
      s += trans[tp * 48 + tg] + emis[(t * 256 + b) * 48 + tg];
    }
  }
#pragma unroll
  for (int d = 32; d; d >>= 1) {
    s += __shfl_xor(s, d, 64);
    cnt += __shfl_xor(cnt, d, 64);
  }
  if (lane == 0) {
    const int lt = tags[b * 512 + cnt - 1];
    num[b] = s + et[lt];
  }
}

// ---------------------------------------------------------------------------
// K5: loss = -mean(num - denom)
// ---------------------------------------------------------------------------
__global__ void k5_loss(const float* __restrict__ num, const float* __restrict__ denom,
                        float* __restrict__ out) {
  const int tid = threadIdx.x;
  float v = num[tid] - denom[tid];
#pragma unroll
  for (int d = 32; d; d >>= 1) v += __shfl_xor(v, d, 64);
  __shared__ float p[4];
  if ((tid & 63) == 0) p[tid >> 6] = v;
  __syncthreads();
  if (tid == 0) out[0] = -(p[0] + p[1] + p[2] + p[3]) * (1.0f / 256.0f);
}

// ---------------------------------------------------------------------------
extern "C" void kernel_launch(void* const* d_in, const int* in_sizes, int n_in,
                              void* d_out, int out_size, void* d_ws, size_t ws_size,
                              hipStream_t stream) {
  (void)in_sizes; (void)n_in; (void)out_size; (void)ws_size;
  const int*   words = (const int*)d_in[0];
  const int*   tags  = (const int*)d_in[1];
  // d_in[2] = mask (bool) -- unused; reconstructed as words != 0
  const float* emb   = (const float*)d_in[3];
  const float* Wih_f = (const float*)d_in[4];
  const float* Whh_f = (const float*)d_in[5];
  const float* bih_f = (const float*)d_in[6];
  const float* bhh_f = (const float*)d_in[7];
  const float* Wih_b = (const float*)d_in[8];
  const float* Whh_b = (const float*)d_in[9];
  const float* bih_b = (const float*)d_in[10];
  const float* bhh_b = (const float*)d_in[11];
  const float* Wout  = (const float*)d_in[12];
  const float* bout  = (const float*)d_in[13];
  const float* trans = (const float*)d_in[14];
  const float* st    = (const float*)d_in[15];
  const float* et    = (const float*)d_in[16];

  char* ws = (char*)d_ws;
  ushort_t* x_bt  = (ushort_t*)(ws);                    // 33,554,432 B
  ushort_t* h_f   = (ushort_t*)(ws + 33554432);         // 33,554,432 B
  ushort_t* h_b   = (ushort_t*)(ws + 67108864);         // 33,554,432 B
  float*    emis  = (float*)   (ws + 100663296);        // 25,165,824 B
  float*    denom = (float*)   (ws + 125829120);        // 1,024 B
  float*    num   = (float*)   (ws + 125830144);        // 1,024 B

  k0_embed<<<65536, 256, 0, stream>>>(words, emb, x_bt);
  k2_lstm <<<256, 512, 0, stream>>>(Wih_f, Whh_f, bih_f, bhh_f,
                                    Wih_b, Whh_b, bih_b, bhh_b,
                                    x_bt, h_f, h_b);
  k3_emis <<<1024, 256, 0, stream>>>(h_f, h_b, Wout, bout, emis);
  k4_den  <<<256, 64, 0, stream>>>(words, emis, trans, st, et, denom);
  k4b_num <<<256, 64, 0, stream>>>(words, tags, emis, trans, st, et, num);
  k5_loss <<<1, 256, 0, stream>>>(num, denom, (float*)d_out);
}

// Round 4
// 745.913 us; speedup vs baseline: 1.6702x; 1.2151x over previous
//
#include <hip/hip_runtime.h>
#include <hip/hip_bf16.h>

// Sizes (fixed by the reference)
//  V=32000, T=48, E=128, HID=256, H=128, B=256, L=512, 4H=512
typedef unsigned short ushort_t;
typedef unsigned int uint_t;
typedef __bf16 bf16x8 __attribute__((ext_vector_type(8)));
typedef float f32x4 __attribute__((ext_vector_type(4)));
typedef float f32x16 __attribute__((ext_vector_type(16)));

#define L2E 1.44269504088896340736f
#define LN2 0.69314718055994530942f

// LDS-only barrier: does NOT drain vmcnt -> global loads/stores stay in flight.
#define WGBAR() __asm__ volatile("s_waitcnt lgkmcnt(0)\n\ts_barrier" ::: "memory")
// In-wave LDS RAW fence for single-wave workgroups.
#define LGKM0() __asm__ volatile("s_waitcnt lgkmcnt(0)" ::: "memory")

static __device__ __forceinline__ float fexp2(float x) { return __builtin_amdgcn_exp2f(x); }
static __device__ __forceinline__ float flog2(float x) { return __builtin_amdgcn_logf(x); }
static __device__ __forceinline__ float frcp (float x) { return __builtin_amdgcn_rcpf(x); }

static __device__ __forceinline__ float sigm(float x) {
  return frcp(1.0f + fexp2(-L2E * x));
}
static __device__ __forceinline__ float tanha(float x) {
  return 1.0f - 2.0f * frcp(1.0f + fexp2(2.0f * L2E * x));
}

static __device__ __forceinline__ ushort_t f2bf(float f) {
  union { float f; uint_t u; } v; v.f = f;
  uint_t u = v.u;
  uint_t r = (u + 0x7fffu + ((u >> 16) & 1u)) >> 16;  // RNE
  return (ushort_t)r;
}
static __device__ __forceinline__ float bf2f(uint_t h) {
  union { uint_t u; float f; } v; v.u = h << 16;
  return v.f;
}
static __device__ __forceinline__ bf16x8 pack8(float4 a, float4 b) {
  uint4 u = make_uint4(
      (uint_t)f2bf(a.x) | ((uint_t)f2bf(a.y) << 16),
      (uint_t)f2bf(a.z) | ((uint_t)f2bf(a.w) << 16),
      (uint_t)f2bf(b.x) | ((uint_t)f2bf(b.y) << 16),
      (uint_t)f2bf(b.z) | ((uint_t)f2bf(b.w) << 16));
  return __builtin_bit_cast(bf16x8, u);
}
static __device__ __forceinline__ bf16x8 zero8() {
  uint4 z = make_uint4(0u, 0u, 0u, 0u);
  return __builtin_bit_cast(bf16x8, z);
}
static __device__ __forceinline__ uint2 pack4(float4 a) {
  return make_uint2((uint_t)f2bf(a.x) | ((uint_t)f2bf(a.y) << 16),
                    (uint_t)f2bf(a.z) | ((uint_t)f2bf(a.w) << 16));
}

// ---------------------------------------------------------------------------
// K2 v4: fully-fused BiLSTM. grid = 256 WGs x 512 thr; wg>>7 = dir,
// (wg&127)*2 = 2 batch rows. Recurrence uses K=128 (h only, 16 MFMA/wave/step);
// the x-projection xp = emb[words] @ Wih^T is PRODUCED IN-KERNEL in dense
// 8-step blocks (M=16 rows = 8t x 2b -> only 2 extra MFMA/wave/step, filling
// the recurrence chain's MFMA-idle bubbles). Everything stays in LDS:
//   hx  [2][2][136]  h double buffer (step parity)
//   xp  [2][16][520] x-projection double buffer (block parity)
//   xs  [2][16][136] staged bf16 x rows for NEXT block's production
// Raw lgkm-only barriers keep global loads/stores in flight across steps.
// ---------------------------------------------------------------------------
__global__ __launch_bounds__(512, 2) void k2_lstm(
    const int* __restrict__ words, const float* __restrict__ emb,
    const float* __restrict__ Wih_f, const float* __restrict__ Whh_f,
    const float* __restrict__ bih_f, const float* __restrict__ bhh_f,
    const float* __restrict__ Wih_b, const float* __restrict__ Whh_b,
    const float* __restrict__ bih_b, const float* __restrict__ bhh_b,
    ushort_t* __restrict__ h_f, ushort_t* __restrict__ h_b) {
  const int wg = blockIdx.x;
  const int dir = wg >> 7;
  const int r0 = (wg & 127) << 1;
  const float* Whh = dir ? Whh_b : Whh_f;
  const float* Wih = dir ? Wih_b : Wih_f;
  const float* bih = dir ? bih_b : bih_f;
  const float* bhh = dir ? bhh_b : bhh_f;
  ushort_t* hout = dir ? h_b : h_f;

  const int tid = threadIdx.x;
  const int w = tid >> 6;        // wave 0..7
  const int lane = tid & 63;
  const int l15 = lane & 15;
  const int kq = lane >> 4;      // 0..3

  __shared__ __align__(16) ushort_t hx[2][2][136];   //  1,088 B
  __shared__ __align__(16) ushort_t xp[2][16][520];  // 33,280 B
  __shared__ __align__(16) ushort_t xs[2][16][136];  //  8,704 B

  // ---- register-resident weight fragments (bf16), [quadrant][K-chunk] ----
  // B layout (16x16x32): col n = lane&15, k = (lane>>4)*8 + j
  bf16x8 wfh[4][4], wfx[4][4];
#pragma unroll
  for (int Q = 0; Q < 4; ++Q) {
    const int n = Q * 128 + w * 16 + l15;
#pragma unroll
    for (int c = 0; c < 4; ++c) {
      const int k0 = c * 32 + kq * 8;
      const float* sh = Whh + n * 128 + k0;
      const float* sx = Wih + n * 128 + k0;
      wfh[Q][c] = pack8(*(const float4*)sh, *(const float4*)(sh + 4));
      wfx[Q][c] = pack8(*(const float4*)sx, *(const float4*)(sx + 4));
    }
  }

  const int ur = (lane >> 4) & 1;
  const int uj = w * 16 + l15;
  float bQ[4];
#pragma unroll
  for (int Q = 0; Q < 4; ++Q) bQ[Q] = bih[Q * 128 + uj] + bhh[Q * 128 + uj];
  float cst = 0.f;

  // staging thread mapping: 512 thr cover 16 rows x 128 cols (4 floats each)
  const int sm = tid >> 5;          // xs row 0..15 -> (tl = sm>>1, r = sm&1)
  const int sc = (tid & 31) * 4;    // col 0..124
  const int str = r0 + (sm & 1);
  const int stl = sm >> 1;

  // ---- prologue ----
  if (tid < 256) hx[0][tid >> 7][tid & 127] = 0;   // h(-1) = 0
  {  // stage xs[1] = x(block 0)
    const int tg = stl;
    const int tf = dir ? (511 - tg) : tg;
    const int word = words[str * 512 + tf];
    float4 av = *(const float4*)(emb + (size_t)word * 128 + sc);
    *(uint2*)&xs[1][sm][sc] = pack4(av);
  }
  WGBAR();
  // produce xp[0] from xs[1] (16 dense MFMAs/wave)
#pragma unroll
  for (int Q = 0; Q < 4; ++Q) {
    f32x4 pc = {0.f, 0.f, 0.f, 0.f};
#pragma unroll
    for (int c = 0; c < 4; ++c) {
      bf16x8 af = __builtin_bit_cast(bf16x8, *(const uint4*)&xs[1][l15][kq * 8 + c * 32]);
      pc = __builtin_amdgcn_mfma_f32_16x16x32_bf16(af, wfx[Q][c], pc, 0, 0, 0);
    }
#pragma unroll
    for (int rr = 0; rr < 4; ++rr)
      xp[0][kq * 4 + rr][Q * 128 + w * 16 + l15] = f2bf(pc[rr]);
  }
  {  // stage xs[0] = x(block 1)
    const int tg = 8 + stl;
    const int tf = dir ? (511 - tg) : tg;
    const int word = words[str * 512 + tf];
    float4 av = *(const float4*)(emb + (size_t)word * 128 + sc);
    *(uint2*)&xs[0][sm][sc] = pack4(av);
  }
  WGBAR();

  int sword = 0;
  float4 se0 = make_float4(0.f, 0.f, 0.f, 0.f);

#pragma unroll 1
  for (int i = 0; i < 64; ++i) {   // 64 blocks of 8 steps
    const int pcon = i & 1;        // consume xp[pcon], production reads xs[pcon]
    const int ppro = pcon ^ 1;     // produce xp[ppro], staging writes xs[ppro]
    f32x4 pc = {0.f, 0.f, 0.f, 0.f};
#pragma unroll
    for (int s = 0; s < 8; ++s) {
      const int t = i * 8 + s;
      const int p = t & 1;
      // xp consumption reads (buffer stable all block; issued early)
      const ushort_t* xrow = &xp[pcon][2 * s + ur][uj];
      const uint_t x0 = xrow[0], x1 = xrow[128], x2 = xrow[256], x3 = xrow[384];
      // staging pipeline for x(block i+2): word @s0, emb @s2, LDS write @s6
      if (i < 62) {
        if (s == 0) {
          const int tg = (i + 2) * 8 + stl;
          const int tf = dir ? (511 - tg) : tg;
          sword = words[str * 512 + tf];
        }
        if (s == 2) se0 = *(const float4*)(emb + (size_t)sword * 128 + sc);
        if (s == 6) *(uint2*)&xs[ppro][sm][sc] = pack4(se0);
      }
      // ---- recurrence MFMAs: gates_h = h @ Whh^T (K=128) ----
      f32x4 a0 = {0.f, 0.f, 0.f, 0.f}, a1 = a0, a2 = a0, a3 = a0;
      const ushort_t* abase = &hx[p][l15 & 1][kq * 8];
#pragma unroll
      for (int c = 0; c < 4; ++c) {
        bf16x8 af = __builtin_bit_cast(bf16x8, *(const uint4*)(abase + c * 32));
        a0 = __builtin_amdgcn_mfma_f32_16x16x32_bf16(af, wfh[0][c], a0, 0, 0, 0);
        a1 = __builtin_amdgcn_mfma_f32_16x16x32_bf16(af, wfh[1][c], a1, 0, 0, 0);
        a2 = __builtin_amdgcn_mfma_f32_16x16x32_bf16(af, wfh[2][c], a2, 0, 0, 0);
        a3 = __builtin_amdgcn_mfma_f32_16x16x32_bf16(af, wfh[3][c], a3, 0, 0, 0);
      }
      // ---- production MFMAs for block i+1 (independent; fills bubbles) ----
      if (i < 63) {
        const int Q = s >> 1;
        if ((s & 1) == 0) {
          pc = f32x4{0.f, 0.f, 0.f, 0.f};
          bf16x8 af0 = __builtin_bit_cast(bf16x8, *(const uint4*)&xs[pcon][l15][kq * 8]);
          bf16x8 af1 = __builtin_bit_cast(bf16x8, *(const uint4*)&xs[pcon][l15][kq * 8 + 32]);
          pc = __builtin_amdgcn_mfma_f32_16x16x32_bf16(af0, wfx[Q][0], pc, 0, 0, 0);
          pc = __builtin_amdgcn_mfma_f32_16x16x32_bf16(af1, wfx[Q][1], pc, 0, 0, 0);
        } else {
          bf16x8 af2 = __builtin_bit_cast(bf16x8, *(const uint4*)&xs[pcon][l15][kq * 8 + 64]);
          bf16x8 af3 = __builtin_bit_cast(bf16x8, *(const uint4*)&xs[pcon][l15][kq * 8 + 96]);
          pc = __builtin_amdgcn_mfma_f32_16x16x32_bf16(af2, wfx[Q][2], pc, 0, 0, 0);
          pc = __builtin_amdgcn_mfma_f32_16x16x32_bf16(af3, wfx[Q][3], pc, 0, 0, 0);
#pragma unroll
          for (int rr = 0; rr < 4; ++rr)
            xp[ppro][kq * 4 + rr][Q * 128 + w * 16 + l15] = f2bf(pc[rr]);
        }
      }
      // ---- redistribute C rows 0,1 -> lanes 0..31 (row=lane>>4, col=lane&15)
      float g0, g1, g2, g3;
      {
        float t0, t1;
        t0 = __shfl(a0[0], l15, 64); t1 = __shfl(a0[1], l15, 64); g0 = (lane < 16) ? t0 : t1;
        t0 = __shfl(a1[0], l15, 64); t1 = __shfl(a1[1], l15, 64); g1 = (lane < 16) ? t0 : t1;
        t0 = __shfl(a2[0], l15, 64); t1 = __shfl(a2[1], l15, 64); g2 = (lane < 16) ? t0 : t1;
        t0 = __shfl(a3[0], l15, 64); t1 = __shfl(a3[1], l15, 64); g3 = (lane < 16) ? t0 : t1;
      }
      g0 += bQ[0] + bf2f(x0);
      g1 += bQ[1] + bf2f(x1);
      g2 += bQ[2] + bf2f(x2);
      g3 += bQ[3] + bf2f(x3);
      // activations (all lanes; only lanes<32 meaningful, stores guarded)
      const float si = sigm(g0), sf = sigm(g1), so = sigm(g3);
      const float tg = tanha(g2);
      cst = sf * cst + si * tg;
      const float h = so * tanha(cst);
      const ushort_t hb = f2bf(h);
      if (lane < 32) {
        hx[p ^ 1][ur][uj] = hb;
        const int tf = dir ? (511 - t) : t;
        hout[(tf * 256 + r0 + ur) * 128 + uj] = hb;  // stays in flight
      }
      WGBAR();
    }
  }
}

// ---------------------------------------------------------------------------
// K3: emis[t*256+b][48] = [h_f|h_b] @ Wout^T + bout  (fp32 out)
// ---------------------------------------------------------------------------
__global__ __launch_bounds__(256, 2) void k3_emis(
    const ushort_t* __restrict__ h_f, const ushort_t* __restrict__ h_b,
    const float* __restrict__ Wout, const float* __restrict__ bout,
    float* __restrict__ emis) {
  const int w = threadIdx.x >> 6;
  const int lane = threadIdx.x & 63;
  const int m31 = lane & 31;
  const int q = lane >> 5;
  const int Mbase = blockIdx.x * 128 + w * 32;

  bf16x8 bfr[2][16];
  float bo[2];
#pragma unroll
  for (int T = 0; T < 2; ++T) {
    const int n = T * 32 + m31;
    if (n < 48) {
      bo[T] = bout[n];
#pragma unroll
      for (int c = 0; c < 16; ++c) {
        const float* src = Wout + n * 256 + c * 16 + q * 8;
        bfr[T][c] = pack8(*(const float4*)src, *(const float4*)(src + 4));
      }
    } else {
      bo[T] = 0.f;
#pragma unroll
      for (int c = 0; c < 16; ++c) bfr[T][c] = zero8();
    }
  }
  f32x16 acc0{}, acc1{};
  const ushort_t* hrf = h_f + (long)(Mbase + m31) * 128;
  const ushort_t* hrb = h_b + (long)(Mbase + m31) * 128;
#pragma unroll
  for (int c = 0; c < 16; ++c) {
    const ushort_t* src = (c < 8) ? (hrf + c * 16 + q * 8) : (hrb + (c - 8) * 16 + q * 8);
    bf16x8 af = __builtin_bit_cast(bf16x8, *(const uint4*)src);
    acc0 = __builtin_amdgcn_mfma_f32_32x32x16_bf16(af, bfr[0][c], acc0, 0, 0, 0);
    acc1 = __builtin_amdgcn_mfma_f32_32x32x16_bf16(af, bfr[1][c], acc1, 0, 0, 0);
  }
#pragma unroll
  for (int T = 0; T < 2; ++T) {
    const int n = T * 32 + m31;
    if (n >= 48) continue;
    f32x16 A = T ? acc1 : acc0;
#pragma unroll
    for (int r = 0; r < 16; ++r) {
      const int row = (r & 3) + ((r >> 2) << 3) + (q << 2);
      emis[(long)(Mbase + row) * 48 + n] = A[r] + bo[T];
    }
  }
}

// ---------------------------------------------------------------------------
// K4 v3: CRF forward in the LINEAR domain with lagged renorm.
//   d <- (d @ P) * E,  P = 2^{trans*L2E} (regs), E = 2^{em*L2E} (off-chain).
// Renorm every 4 steps: exponent of lagged max folds into E; int S tracks it.
// No exp/log/max on the per-step chain. 256 WGs x 64 thr (single wave).
// ---------------------------------------------------------------------------
__global__ void k4_den(const int* __restrict__ words, const float* __restrict__ emis,
                       const float* __restrict__ trans, const float* __restrict__ st,
                       const float* __restrict__ et, float* __restrict__ denom) {
  const int b = blockIdx.x;
  const int j = threadIdx.x;
  const bool v = j < 48;
  const int jj = v ? j : 47;
  float pcol[48];
#pragma unroll
  for (int i = 0; i < 48; ++i) pcol[i] = fexp2(trans[i * 48 + jj] * L2E);

  __shared__ __align__(16) float ul[64];
  float d = v ? fexp2((st[j] + emis[b * 48 + j]) * L2E) : 0.f;
  int S = 0, e_pend = 0;

  float em0 = v ? emis[(1 * 256 + b) * 48 + j] : 0.f;
  float em1 = v ? emis[(2 * 256 + b) * 48 + j] : 0.f;
  float em2 = v ? emis[(3 * 256 + b) * 48 + j] : 0.f;
  int wv0 = words[b * 512 + 1];
  int wv1 = words[b * 512 + 2];
  int wv2 = words[b * 512 + 3];
  float Ecur = fexp2(em0 * L2E);

#pragma unroll 1
  for (int t = 1; t < 512; ++t) {
    float E = Ecur;
    int eApp = 0;
    if ((t & 3) == 2) { E = ldexpf(E, -e_pend); eApp = e_pend; }  // fold renorm
    const int wv = wv0;
    const int tn = min(511, t + 3);
    em0 = em1; em1 = em2;
    em2 = v ? emis[(tn * 256 + b) * 48 + j] : 0.f;
    wv0 = wv1; wv1 = wv2; wv2 = words[b * 512 + tn];
    const float En = fexp2(em0 * L2E);  // E for t+1, off the chain

    ul[j] = d;
    LGKM0();
    float s0 = 0.f, s1 = 0.f, s2 = 0.f, s3 = 0.f;
#pragma unroll
    for (int i4 = 0; i4 < 12; ++i4) {
      float4 uu = *(const float4*)&ul[i4 * 4];
      s0 = fmaf(uu.x, pcol[i4 * 4 + 0], s0);
      s1 = fmaf(uu.y, pcol[i4 * 4 + 1], s1);
      s2 = fmaf(uu.z, pcol[i4 * 4 + 2], s2);
      s3 = fmaf(uu.w, pcol[i4 * 4 + 3], s3);
    }
    const float nxt = ((s0 + s1) + (s2 + s3)) * E;
    if (wv != 0) {            // wave-uniform
      d = v ? nxt : 0.f;
      S += eApp;
    }
    if ((t & 3) == 0) {       // lagged measurement (folded 2 steps later)
      float M = d;
#pragma unroll
      for (int dd = 32; dd; dd >>= 1) M = fmaxf(M, __shfl_xor(M, dd, 64));
      e_pend = (__builtin_bit_cast(int, M) >> 23) - 127;
    }
    Ecur = En;
  }
  float uf = v ? d * fexp2(et[j] * L2E) : 0.f;
#pragma unroll
  for (int dd = 32; dd; dd >>= 1) uf += __shfl_xor(uf, dd, 64);
  if (j == 0) denom[b] = ((float)S + flog2(uf)) * LN2;
}

// ---------------------------------------------------------------------------
// K4b: CRF numerator (gold path score).
// ---------------------------------------------------------------------------
__global__ void k4b_num(const int* __restrict__ words, const int* __restrict__ tags,
                        const float* __restrict__ emis, const float* __restrict__ trans,
                        const float* __restrict__ st, const float* __restrict__ et,
                        float* __restrict__ num) {
  const int b = blockIdx.x;
  const int lane = threadIdx.x;
  float s = 0.f;
  int cnt = 0;
#pragma unroll 1
  for (int s8 = 0; s8 < 8; ++s8) {
    const int t = lane + (s8 << 6);
    const int wv = words[b * 512 + t];
    const int tg = tags[b * 512 + t];
    const bool mt = (wv != 0);
    cnt += mt ? 1 : 0;
    if (t == 0) {
      s += st[tg] + emis[b * 48 + tg];
    } else if (mt) {
      const int tp = tags[b * 512 + t - 1];
      s += trans[tp * 48 + tg] + emis[(t * 256 + b) * 48 + tg];
    }
  }
#pragma unroll
  for (int d = 32; d; d >>= 1) {
    s += __shfl_xor(s, d, 64);
    cnt += __shfl_xor(cnt, d, 64);
  }
  if (lane == 0) {
    const int lt = tags[b * 512 + cnt - 1];
    num[b] = s + et[lt];
  }
}

// ---------------------------------------------------------------------------
// K5: loss = -mean(num - denom)
// ---------------------------------------------------------------------------
__global__ void k5_loss(const float* __restrict__ num, const float* __restrict__ denom,
                        float* __restrict__ out) {
  const int tid = threadIdx.x;
  float v = num[tid] - denom[tid];
#pragma unroll
  for (int d = 32; d; d >>= 1) v += __shfl_xor(v, d, 64);
  __shared__ float p[4];
  if ((tid & 63) == 0) p[tid >> 6] = v;
  __syncthreads();
  if (tid == 0) out[0] = -(p[0] + p[1] + p[2] + p[3]) * (1.0f / 256.0f);
}

// ---------------------------------------------------------------------------
extern "C" void kernel_launch(void* const* d_in, const int* in_sizes, int n_in,
                              void* d_out, int out_size, void* d_ws, size_t ws_size,
                              hipStream_t stream) {
  (void)in_sizes; (void)n_in; (void)out_size; (void)ws_size;
  const int*   words = (const int*)d_in[0];
  const int*   tags  = (const int*)d_in[1];
  // d_in[2] = mask (bool) -- unused; reconstructed as words != 0
  const float* emb   = (const float*)d_in[3];
  const float* Wih_f = (const float*)d_in[4];
  const float* Whh_f = (const float*)d_in[5];
  const float* bih_f = (const float*)d_in[6];
  const float* bhh_f = (const float*)d_in[7];
  const float* Wih_b = (const float*)d_in[8];
  const float* Whh_b = (const float*)d_in[9];
  const float* bih_b = (const float*)d_in[10];
  const float* bhh_b = (const float*)d_in[11];
  const float* Wout  = (const float*)d_in[12];
  const float* bout  = (const float*)d_in[13];
  const float* trans = (const float*)d_in[14];
  const float* st    = (const float*)d_in[15];
  const float* et    = (const float*)d_in[16];

  char* ws = (char*)d_ws;
  ushort_t* h_f   = (ushort_t*)(ws);                    // 33,554,432 B
  ushort_t* h_b   = (ushort_t*)(ws + 33554432);         // 33,554,432 B
  float*    emis  = (float*)   (ws + 67108864);         // 25,165,824 B
  float*    denom = (float*)   (ws + 92274688);         //      1,024 B
  float*    num   = (float*)   (ws + 92275712);         //      1,024 B
  // total ws needed: ~92.3 MB (within the known-good 125.8 MB envelope)

  k2_lstm <<<256, 512, 0, stream>>>(words, emb,
                                    Wih_f, Whh_f, bih_f, bhh_f,
                                    Wih_b, Whh_b, bih_b, bhh_b,
                                    h_f, h_b);
  k3_emis <<<1024, 256, 0, stream>>>(h_f, h_b, Wout, bout, emis);
  k4_den  <<<256, 64, 0, stream>>>(words, emis, trans, st, et, denom);
  k4b_num <<<256, 64, 0, stream>>>(words, tags, emis, trans, st, et, num);
  k5_loss <<<1, 256, 0, stream>>>(num, denom, (float*)d_out);
}

// Round 5
// 659.906 us; speedup vs baseline: 1.8879x; 1.1303x over previous
//
#include <hip/hip_runtime.h>
#include <hip/hip_bf16.h>

// Sizes (fixed by the reference)
//  V=32000, T=48, E=128, HID=256, H=128, B=256, L=512, 4H=512
typedef unsigned short ushort_t;
typedef unsigned int uint_t;
typedef __bf16 bf16x8 __attribute__((ext_vector_type(8)));
typedef float f32x4 __attribute__((ext_vector_type(4)));
typedef float f32x16 __attribute__((ext_vector_type(16)));

#define L2E 1.44269504088896340736f
#define LN2 0.69314718055994530942f

// LDS-only barrier: does NOT drain vmcnt -> global loads/stores stay in flight.
#define WGBAR() __asm__ volatile("s_waitcnt lgkmcnt(0)\n\ts_barrier" ::: "memory")
// In-wave LDS RAW fence for single-wave workgroups.
#define LGKM0() __asm__ volatile("s_waitcnt lgkmcnt(0)" ::: "memory")

static __device__ __forceinline__ float fexp2(float x) { return __builtin_amdgcn_exp2f(x); }
static __device__ __forceinline__ float flog2(float x) { return __builtin_amdgcn_logf(x); }
static __device__ __forceinline__ float frcp (float x) { return __builtin_amdgcn_rcpf(x); }

static __device__ __forceinline__ float sigm(float x) {
  return frcp(1.0f + fexp2(-L2E * x));
}
static __device__ __forceinline__ float tanha(float x) {
  return 1.0f - 2.0f * frcp(1.0f + fexp2(2.0f * L2E * x));
}

static __device__ __forceinline__ ushort_t f2bf(float f) {
  union { float f; uint_t u; } v; v.f = f;
  uint_t u = v.u;
  uint_t r = (u + 0x7fffu + ((u >> 16) & 1u)) >> 16;  // RNE
  return (ushort_t)r;
}
static __device__ __forceinline__ float bf2f(uint_t h) {
  union { uint_t u; float f; } v; v.u = h << 16;
  return v.f;
}
static __device__ __forceinline__ bf16x8 pack8(float4 a, float4 b) {
  uint4 u = make_uint4(
      (uint_t)f2bf(a.x) | ((uint_t)f2bf(a.y) << 16),
      (uint_t)f2bf(a.z) | ((uint_t)f2bf(a.w) << 16),
      (uint_t)f2bf(b.x) | ((uint_t)f2bf(b.y) << 16),
      (uint_t)f2bf(b.z) | ((uint_t)f2bf(b.w) << 16));
  return __builtin_bit_cast(bf16x8, u);
}
static __device__ __forceinline__ bf16x8 zero8() {
  uint4 z = make_uint4(0u, 0u, 0u, 0u);
  return __builtin_bit_cast(bf16x8, z);
}
static __device__ __forceinline__ uint2 pack4(float4 a) {
  return make_uint2((uint_t)f2bf(a.x) | ((uint_t)f2bf(a.y) << 16),
                    (uint_t)f2bf(a.z) | ((uint_t)f2bf(a.w) << 16));
}

// ---------------------------------------------------------------------------
// K2 v5: fully-fused BiLSTM. grid = 256 WGs x 512 thr; wg>>7 = dir,
// (wg&127)*2 = 2 batch rows. Recurrence K=128 (16 MFMA/wave/step); the
// x-projection xp = emb[words] @ Wih^T + bias is produced in-kernel in dense
// 8-step blocks (2 MFMA/wave/step, fills recurrence bubbles). v5 changes:
//  - xp layout [16][128][4]: consumption is one ds_read_b64 (was 4x u16)
//  - bias folded into production MFMA C-init (act chain shorter)
//  - gate redistribution: 4 bpermutes (lanes<16 use own a*[0] row-0 regs)
// Raw lgkm-only barriers keep global loads/stores in flight across steps.
// ---------------------------------------------------------------------------
__global__ __launch_bounds__(512, 2) void k2_lstm(
    const int* __restrict__ words, const float* __restrict__ emb,
    const float* __restrict__ Wih_f, const float* __restrict__ Whh_f,
    const float* __restrict__ bih_f, const float* __restrict__ bhh_f,
    const float* __restrict__ Wih_b, const float* __restrict__ Whh_b,
    const float* __restrict__ bih_b, const float* __restrict__ bhh_b,
    ushort_t* __restrict__ h_f, ushort_t* __restrict__ h_b) {
  const int wg = blockIdx.x;
  const int dir = wg >> 7;
  const int r0 = (wg & 127) << 1;
  const float* Whh = dir ? Whh_b : Whh_f;
  const float* Wih = dir ? Wih_b : Wih_f;
  const float* bih = dir ? bih_b : bih_f;
  const float* bhh = dir ? bhh_b : bhh_f;
  ushort_t* hout = dir ? h_b : h_f;

  const int tid = threadIdx.x;
  const int w = tid >> 6;        // wave 0..7
  const int lane = tid & 63;
  const int l15 = lane & 15;
  const int kq = lane >> 4;      // 0..3

  __shared__ __align__(16) ushort_t hx[2][2][136];      //  1,088 B
  __shared__ __align__(16) ushort_t xp[2][16][128][4];  // 32,768 B
  __shared__ __align__(16) ushort_t xs[2][16][136];     //  8,704 B

  // ---- register-resident weight fragments (bf16), [quadrant][K-chunk] ----
  // B layout (16x16x32): col n = lane&15, k = (lane>>4)*8 + j
  bf16x8 wfh[4][4], wfx[4][4];
  float biasP[4];   // production bias for col w*16+l15, quadrant Q
#pragma unroll
  for (int Q = 0; Q < 4; ++Q) {
    const int n = Q * 128 + w * 16 + l15;
    biasP[Q] = bih[n] + bhh[n];
#pragma unroll
    for (int c = 0; c < 4; ++c) {
      const int k0 = c * 32 + kq * 8;
      const float* sh = Whh + n * 128 + k0;
      const float* sx = Wih + n * 128 + k0;
      wfh[Q][c] = pack8(*(const float4*)sh, *(const float4*)(sh + 4));
      wfx[Q][c] = pack8(*(const float4*)sx, *(const float4*)(sx + 4));
    }
  }

  const int ur = (lane >> 4) & 1;
  const int uj = w * 16 + l15;
  float cst = 0.f;

  // staging thread mapping: 512 thr cover 16 rows x 128 cols (4 floats each)
  const int sm = tid >> 5;          // xs row 0..15  (tl = sm>>1, r = sm&1)
  const int sc = (tid & 31) * 4;    // col 0..124
  const int str = r0 + (sm & 1);
  const int stl = sm >> 1;

  // ---- prologue ----
  if (tid < 256) hx[0][tid >> 7][tid & 127] = 0;   // h(-1) = 0
  {  // stage xs[1] = x(block 0)
    const int tg = stl;
    const int tf = dir ? (511 - tg) : tg;
    const int word = words[str * 512 + tf];
    float4 av = *(const float4*)(emb + (size_t)word * 128 + sc);
    *(uint2*)&xs[1][sm][sc] = pack4(av);
  }
  WGBAR();
  // produce xp[0] from xs[1] (16 dense MFMAs/wave), bias in C-init
#pragma unroll
  for (int Q = 0; Q < 4; ++Q) {
    f32x4 pc = {biasP[Q], biasP[Q], biasP[Q], biasP[Q]};
#pragma unroll
    for (int c = 0; c < 4; ++c) {
      bf16x8 af = __builtin_bit_cast(bf16x8, *(const uint4*)&xs[1][l15][kq * 8 + c * 32]);
      pc = __builtin_amdgcn_mfma_f32_16x16x32_bf16(af, wfx[Q][c], pc, 0, 0, 0);
    }
#pragma unroll
    for (int rr = 0; rr < 4; ++rr)
      xp[0][kq * 4 + rr][w * 16 + l15][Q] = f2bf(pc[rr]);
  }
  {  // stage xs[0] = x(block 1)
    const int tg = 8 + stl;
    const int tf = dir ? (511 - tg) : tg;
    const int word = words[str * 512 + tf];
    float4 av = *(const float4*)(emb + (size_t)word * 128 + sc);
    *(uint2*)&xs[0][sm][sc] = pack4(av);
  }
  WGBAR();

  int sword = 0;
  float4 se0 = make_float4(0.f, 0.f, 0.f, 0.f);

#pragma unroll 1
  for (int i = 0; i < 64; ++i) {   // 64 blocks of 8 steps
    const int pcon = i & 1;        // consume xp[pcon]; production reads xs[pcon]
    const int ppro = pcon ^ 1;     // produce xp[ppro]; staging writes xs[ppro]
    f32x4 pc = {0.f, 0.f, 0.f, 0.f};
#pragma unroll
    for (int s = 0; s < 8; ++s) {
      const int t = i * 8 + s;
      const int p = t & 1;
      // xp consumption: one b64 read (Q0..Q3 packed), used after shuffles
      const uint2 xq = *(const uint2*)&xp[pcon][2 * s + ur][uj][0];
      // staging pipeline for x(block i+2): word @s0, emb @s2, LDS write @s6
      if (i < 62) {
        if (s == 0) {
          const int tg = (i + 2) * 8 + stl;
          const int tf = dir ? (511 - tg) : tg;
          sword = words[str * 512 + tf];
        }
        if (s == 2) se0 = *(const float4*)(emb + (size_t)sword * 128 + sc);
        if (s == 6) *(uint2*)&xs[ppro][sm][sc] = pack4(se0);
      }
      // ---- recurrence MFMAs: gates_h = h @ Whh^T (K=128) ----
      f32x4 a0 = {0.f, 0.f, 0.f, 0.f}, a1 = a0, a2 = a0, a3 = a0;
      const ushort_t* abase = &hx[p][l15 & 1][kq * 8];
#pragma unroll
      for (int c = 0; c < 4; ++c) {
        bf16x8 af = __builtin_bit_cast(bf16x8, *(const uint4*)(abase + c * 32));
        a0 = __builtin_amdgcn_mfma_f32_16x16x32_bf16(af, wfh[0][c], a0, 0, 0, 0);
        a1 = __builtin_amdgcn_mfma_f32_16x16x32_bf16(af, wfh[1][c], a1, 0, 0, 0);
        a2 = __builtin_amdgcn_mfma_f32_16x16x32_bf16(af, wfh[2][c], a2, 0, 0, 0);
        a3 = __builtin_amdgcn_mfma_f32_16x16x32_bf16(af, wfh[3][c], a3, 0, 0, 0);
      }
      // ---- production MFMAs for block i+1 (independent; fills bubbles) ----
      if (i < 63) {
        const int Q = s >> 1;
        if ((s & 1) == 0) {
          pc = f32x4{biasP[Q], biasP[Q], biasP[Q], biasP[Q]};
          bf16x8 af0 = __builtin_bit_cast(bf16x8, *(const uint4*)&xs[pcon][l15][kq * 8]);
          bf16x8 af1 = __builtin_bit_cast(bf16x8, *(const uint4*)&xs[pcon][l15][kq * 8 + 32]);
          pc = __builtin_amdgcn_mfma_f32_16x16x32_bf16(af0, wfx[Q][0], pc, 0, 0, 0);
          pc = __builtin_amdgcn_mfma_f32_16x16x32_bf16(af1, wfx[Q][1], pc, 0, 0, 0);
        } else {
          bf16x8 af2 = __builtin_bit_cast(bf16x8, *(const uint4*)&xs[pcon][l15][kq * 8 + 64]);
          bf16x8 af3 = __builtin_bit_cast(bf16x8, *(const uint4*)&xs[pcon][l15][kq * 8 + 96]);
          pc = __builtin_amdgcn_mfma_f32_16x16x32_bf16(af2, wfx[Q][2], pc, 0, 0, 0);
          pc = __builtin_amdgcn_mfma_f32_16x16x32_bf16(af3, wfx[Q][3], pc, 0, 0, 0);
#pragma unroll
          for (int rr = 0; rr < 4; ++rr)
            xp[ppro][kq * 4 + rr][w * 16 + l15][Q] = f2bf(pc[rr]);
        }
      }
      // ---- redistribute: lanes<16 own row-0 gates (a*[0]); lanes 16-31
      //      fetch row-1 gates (a*[1]) from lane l15 -> 4 bpermutes only.
      float g0, g1, g2, g3;
      {
        const float s0 = __shfl(a0[1], l15, 64);
        const float s1 = __shfl(a1[1], l15, 64);
        const float s2 = __shfl(a2[1], l15, 64);
        const float s3 = __shfl(a3[1], l15, 64);
        g0 = (lane < 16) ? a0[0] : s0;
        g1 = (lane < 16) ? a1[0] : s1;
        g2 = (lane < 16) ? a2[0] : s2;
        g3 = (lane < 16) ? a3[0] : s3;
      }
      // add xp (bias already folded into xp at production)
      g0 += __builtin_bit_cast(float, xq.x << 16);
      g1 += __builtin_bit_cast(float, xq.x & 0xffff0000u);
      g2 += __builtin_bit_cast(float, xq.y << 16);
      g3 += __builtin_bit_cast(float, xq.y & 0xffff0000u);
      // activations (all lanes; only lanes<32 meaningful, stores guarded)
      const float si = sigm(g0), sf = sigm(g1), so = sigm(g3);
      const float tg = tanha(g2);
      cst = sf * cst + si * tg;
      const float h = so * tanha(cst);
      const ushort_t hb = f2bf(h);
      if (lane < 32) {
        hx[p ^ 1][ur][uj] = hb;
        const int tf = dir ? (511 - t) : t;
        hout[(tf * 256 + r0 + ur) * 128 + uj] = hb;  // stays in flight
      }
      WGBAR();
    }
  }
}

// ---------------------------------------------------------------------------
// K3: emis[t*256+b][48] = [h_f|h_b] @ Wout^T + bout  (fp32 out)
// ---------------------------------------------------------------------------
__global__ __launch_bounds__(256, 2) void k3_emis(
    const ushort_t* __restrict__ h_f, const ushort_t* __restrict__ h_b,
    const float* __restrict__ Wout, const float* __restrict__ bout,
    float* __restrict__ emis) {
  const int w = threadIdx.x >> 6;
  const int lane = threadIdx.x & 63;
  const int m31 = lane & 31;
  const int q = lane >> 5;
  const int Mbase = blockIdx.x * 128 + w * 32;

  bf16x8 bfr[2][16];
  float bo[2];
#pragma unroll
  for (int T = 0; T < 2; ++T) {
    const int n = T * 32 + m31;
    if (n < 48) {
      bo[T] = bout[n];
#pragma unroll
      for (int c = 0; c < 16; ++c) {
        const float* src = Wout + n * 256 + c * 16 + q * 8;
        bfr[T][c] = pack8(*(const float4*)src, *(const float4*)(src + 4));
      }
    } else {
      bo[T] = 0.f;
#pragma unroll
      for (int c = 0; c < 16; ++c) bfr[T][c] = zero8();
    }
  }
  f32x16 acc0{}, acc1{};
  const ushort_t* hrf = h_f + (long)(Mbase + m31) * 128;
  const ushort_t* hrb = h_b + (long)(Mbase + m31) * 128;
#pragma unroll
  for (int c = 0; c < 16; ++c) {
    const ushort_t* src = (c < 8) ? (hrf + c * 16 + q * 8) : (hrb + (c - 8) * 16 + q * 8);
    bf16x8 af = __builtin_bit_cast(bf16x8, *(const uint4*)src);
    acc0 = __builtin_amdgcn_mfma_f32_32x32x16_bf16(af, bfr[0][c], acc0, 0, 0, 0);
    acc1 = __builtin_amdgcn_mfma_f32_32x32x16_bf16(af, bfr[1][c], acc1, 0, 0, 0);
  }
#pragma unroll
  for (int T = 0; T < 2; ++T) {
    const int n = T * 32 + m31;
    if (n >= 48) continue;
    f32x16 A = T ? acc1 : acc0;
#pragma unroll
    for (int r = 0; r < 16; ++r) {
      const int row = (r & 3) + ((r >> 2) << 3) + (q << 2);
      emis[(long)(Mbase + row) * 48 + n] = A[r] + bo[T];
    }
  }
}

// ---------------------------------------------------------------------------
// K4 v4: CRF forward, linear domain.  d <- (d @ P) * E.
//  - words mask precomputed as 8 ballot u64s (SGPR): zero in-loop memory for
//    the mask (the R3 version's s_load of words was drained by every LGKM0).
//  - renorm every 8 steps via readfirstlane exponent (d_j spread bounded by
//    P's dynamic range, so any lane's exponent works); folded 2 steps later.
// 256 WGs x 64 thr (single wave).
// ---------------------------------------------------------------------------
__global__ void k4_den(const int* __restrict__ words, const float* __restrict__ emis,
                       const float* __restrict__ trans, const float* __restrict__ st,
                       const float* __restrict__ et, float* __restrict__ denom) {
  const int b = blockIdx.x;
  const int j = threadIdx.x;
  const bool v = j < 48;
  const int jj = v ? j : 47;
  float pcol[48];
#pragma unroll
  for (int i = 0; i < 48; ++i) pcol[i] = fexp2(trans[i * 48 + jj] * L2E);

  // mask bits: mb[q] bit s = (words[b*512 + q*64 + s] != 0)
  unsigned long long mb[8];
#pragma unroll
  for (int q = 0; q < 8; ++q)
    mb[q] = __ballot(words[b * 512 + q * 64 + j] != 0);

  __shared__ __align__(16) float ul[64];
  float d = v ? fexp2((st[j] + emis[b * 48 + j]) * L2E) : 0.f;
  int S = 0, e_pend = 0;

  float em0 = v ? emis[(1 * 256 + b) * 48 + j] : 0.f;
  float em1 = v ? emis[(2 * 256 + b) * 48 + j] : 0.f;
  float em2 = v ? emis[(3 * 256 + b) * 48 + j] : 0.f;
  float Ecur = fexp2(em0 * L2E);

#pragma unroll 1
  for (int q = 0; q < 8; ++q) {
    const unsigned long long m = mb[q];
    const int s0 = (q == 0) ? 1 : 0;
#pragma unroll 1
    for (int s = s0; s < 64; ++s) {
      const int t = q * 64 + s;
      float E = Ecur;
      int eApp = 0;
      if ((s & 7) == 2) {   // fold lagged renorm into E (uniform branch)
        const float sc = __builtin_bit_cast(float, (uint_t)(127 - e_pend) << 23);
        E *= sc;
        eApp = e_pend;
      }
      const int tn = min(511, t + 3);
      em0 = em1; em1 = em2;
      em2 = v ? emis[(tn * 256 + b) * 48 + j] : 0.f;   // vmcnt path, depth-3
      const float En = fexp2(em0 * L2E);               // E for t+1, off-chain

      ul[j] = d;
      LGKM0();
      float sA = 0.f, sB = 0.f, sC = 0.f, sD = 0.f;
#pragma unroll
      for (int i4 = 0; i4 < 12; ++i4) {
        float4 uu = *(const float4*)&ul[i4 * 4];
        sA = fmaf(uu.x, pcol[i4 * 4 + 0], sA);
        sB = fmaf(uu.y, pcol[i4 * 4 + 1], sB);
        sC = fmaf(uu.z, pcol[i4 * 4 + 2], sC);
        sD = fmaf(uu.w, pcol[i4 * 4 + 3], sD);
      }
      const float nxt = ((sA + sB) + (sC + sD)) * E;
      if ((m >> s) & 1ull) {   // wave-uniform scalar branch, no memory
        d = v ? nxt : 0.f;
        S += eApp;
      }
      if ((s & 7) == 0) {      // lagged exponent measurement (any lane works)
        const int db = __builtin_amdgcn_readfirstlane(__builtin_bit_cast(int, d));
        e_pend = ((db >> 23) & 0xff) - 127;
      }
      Ecur = En;
    }
  }
  float uf = v ? d * fexp2(et[j] * L2E) : 0.f;
#pragma unroll
  for (int dd = 32; dd; dd >>= 1) uf += __shfl_xor(uf, dd, 64);
  if (j == 0) denom[b] = ((float)S + flog2(uf)) * LN2;
}

// ---------------------------------------------------------------------------
// K4b: CRF numerator (gold path score).
// ---------------------------------------------------------------------------
__global__ void k4b_num(const int* __restrict__ words, const int* __restrict__ tags,
                        const float* __restrict__ emis, const float* __restrict__ trans,
                        const float* __restrict__ st, const float* __restrict__ et,
                        float* __restrict__ num) {
  const int b = blockIdx.x;
  const int lane = threadIdx.x;
  float s = 0.f;
  int cnt = 0;
#pragma unroll 1
  for (int s8 = 0; s8 < 8; ++s8) {
    const int t = lane + (s8 << 6);
    const int wv = words[b * 512 + t];
    const int tg = tags[b * 512 + t];
    const bool mt = (wv != 0);
    cnt += mt ? 1 : 0;
    if (t == 0) {
      s += st[tg] + emis[b * 48 + tg];
    } else if (mt) {
      const int tp = tags[b * 512 + t - 1];
      s += trans[tp * 48 + tg] + emis[(t * 256 + b) * 48 + tg];
    }
  }
#pragma unroll
  for (int d = 32; d; d >>= 1) {
    s += __shfl_xor(s, d, 64);
    cnt += __shfl_xor(cnt, d, 64);
  }
  if (lane == 0) {
    const int lt = tags[b * 512 + cnt - 1];
    num[b] = s + et[lt];
  }
}

// ---------------------------------------------------------------------------
// K5: loss = -mean(num - denom)
// ---------------------------------------------------------------------------
__global__ void k5_loss(const float* __restrict__ num, const float* __restrict__ denom,
                        float* __restrict__ out) {
  const int tid = threadIdx.x;
  float v = num[tid] - denom[tid];
#pragma unroll
  for (int d = 32; d; d >>= 1) v += __shfl_xor(v, d, 64);
  __shared__ float p[4];
  if ((tid & 63) == 0) p[tid >> 6] = v;
  __syncthreads();
  if (tid == 0) out[0] = -(p[0] + p[1] + p[2] + p[3]) * (1.0f / 256.0f);
}

// ---------------------------------------------------------------------------
extern "C" void kernel_launch(void* const* d_in, const int* in_sizes, int n_in,
                              void* d_out, int out_size, void* d_ws, size_t ws_size,
                              hipStream_t stream) {
  (void)in_sizes; (void)n_in; (void)out_size; (void)ws_size;
  const int*   words = (const int*)d_in[0];
  const int*   tags  = (const int*)d_in[1];
  // d_in[2] = mask (bool) -- unused; reconstructed as words != 0
  const float* emb   = (const float*)d_in[3];
  const float* Wih_f = (const float*)d_in[4];
  const float* Whh_f = (const float*)d_in[5];
  const float* bih_f = (const float*)d_in[6];
  const float* bhh_f = (const float*)d_in[7];
  const float* Wih_b = (const float*)d_in[8];
  const float* Whh_b = (const float*)d_in[9];
  const float* bih_b = (const float*)d_in[10];
  const float* bhh_b = (const float*)d_in[11];
  const float* Wout  = (const float*)d_in[12];
  const float* bout  = (const float*)d_in[13];
  const float* trans = (const float*)d_in[14];
  const float* st    = (const float*)d_in[15];
  const float* et    = (const float*)d_in[16];

  char* ws = (char*)d_ws;
  ushort_t* h_f   = (ushort_t*)(ws);                    // 33,554,432 B
  ushort_t* h_b   = (ushort_t*)(ws + 33554432);         // 33,554,432 B
  float*    emis  = (float*)   (ws + 67108864);         // 25,165,824 B
  float*    denom = (float*)   (ws + 92274688);         //      1,024 B
  float*    num   = (float*)   (ws + 92275712);         //      1,024 B
  // total ws needed: ~92.3 MB (within the known-good 125.8 MB envelope)

  k2_lstm <<<256, 512, 0, stream>>>(words, emb,
                                    Wih_f, Whh_f, bih_f, bhh_f,
                                    Wih_b, Whh_b, bih_b, bhh_b,
                                    h_f, h_b);
  k3_emis <<<1024, 256, 0, stream>>>(h_f, h_b, Wout, bout, emis);
  k4_den  <<<256, 64, 0, stream>>>(words, emis, trans, st, et, denom);
  k4b_num <<<256, 64, 0, stream>>>(words, tags, emis, trans, st, et, num);
  k5_loss <<<1, 256, 0, stream>>>(num, denom, (float*)d_out);
}